// Round 12
// baseline (304.785 us; speedup 1.0000x reference)
//
#include <hip/hip_runtime.h>

#define SEQ 2048
#define HEADS 16
#define DEPTH 64
#define DIMS 1024
#define LOG2E 1.44269504088896340736f
#define NROWS 65536            // total q rows = 2*16*2048
#define HTILES 16              // 1024 keys per half / 64

typedef _Float16 f16x8 __attribute__((ext_vector_type(8)));
typedef __fp16 fp16v2 __attribute__((ext_vector_type(2)));
typedef float f32x16 __attribute__((ext_vector_type(16)));

__device__ __forceinline__ f32x16 mfma32(f16x8 a, f16x8 b, f32x16 c) {
  return __builtin_amdgcn_mfma_f32_32x32x16_f16(a, b, c, 0, 0, 0);
}

#if __has_builtin(__builtin_amdgcn_exp2f)
#define EXP2(x) __builtin_amdgcn_exp2f(x)
#else
#define EXP2(x) exp2f(x)
#endif

__device__ __forceinline__ unsigned pkbits(float a, float b) {
  union { fp16v2 h; unsigned u; } cv;
  cv.h = __builtin_amdgcn_cvt_pkrtz(a, b);
  return cv.u;
}

// direct global->LDS DMA, 16B/lane; LDS dest = wave-uniform base + lane*16
#define GLOAD_LDS(g, l)                                                        \
  __builtin_amdgcn_global_load_lds(                                            \
      (const __attribute__((address_space(1))) unsigned int*)(g),              \
      (__attribute__((address_space(3))) unsigned int*)(l), 16, 0, 0)

// ---------- fused prepass: K -> fp16 [bh][S][D];  V -> fp16 [bh][D][S] ------
__global__ __launch_bounds__(256) void prep_kv(const float* __restrict__ k,
                                               const float* __restrict__ v,
                                               _Float16* __restrict__ khf,
                                               _Float16* __restrict__ vtp) {
  const int bid = blockIdx.x;
  if (bid < 2048) {              // ---- K half: one thread per 8 elems ----
    int t = bid * 256 + threadIdx.x;
    size_t flat = (size_t)t * 8;
    int b = (int)(flat >> 21);                    // S*DIMS = 2^21
    int rem = (int)(flat & ((1u << 21) - 1));
    int s = rem >> 10;
    int c = rem & 1023;
    int h = c >> 6;
    int d = c & 63;
    float4 a0 = *(const float4*)(k + flat);
    float4 a1 = *(const float4*)(k + flat + 4);
    float f[8] = {a0.x, a0.y, a0.z, a0.w, a1.x, a1.y, a1.z, a1.w};
    f16x8 th;
    #pragma unroll
    for (int j = 0; j < 8; ++j) th[j] = (_Float16)f[j];
    size_t o = ((size_t)(b * HEADS + h) * SEQ + s) * DEPTH + d;
    *(f16x8*)(khf + o) = th;
  } else {                       // ---- V half: transpose to [bh][D][S] ----
    int t = (bid - 2048) * 256 + threadIdx.x;
    int d = t & 63;
    int sg = (t >> 6) & 255;
    int bh = t >> 14;
    int b = bh >> 4, h = bh & 15;
    int s0 = sg * 8;
    const float* src = v + ((size_t)(b * SEQ + s0)) * DIMS + h * DEPTH + d;
    _Float16* dst = vtp + ((size_t)bh * DEPTH + d) * SEQ + s0;
    f16x8 tv;
    #pragma unroll
    for (int i = 0; i < 8; ++i) tv[i] = (_Float16)src[(size_t)i * DIMS];
    *(f16x8*)dst = tv;
  }
}

// ---------- main: flash attention, split-K x2, 32x32x16 MFMA ----------
// Each block handles 1024 keys (half the sequence) for 128 q-rows, writing
// normalized fp16 partial O + per-row (m, den) stats. LDS swizzle: 16B chunk
// c of row r at chunk c ^ ((r&7)^((r>>3)&3)) -> conflict-free b128 reads.
// P stays in registers (cvt_pk + v_permlane32_swap). den via ones-MFMA.
__global__ __launch_bounds__(256, 4) void attn_fwd(
    const float* __restrict__ q, const _Float16* __restrict__ kh,
    const _Float16* __restrict__ vt, _Float16* __restrict__ opart,
    float2* __restrict__ stats) {
  __shared__ _Float16 Kl[2][64 * 64];
  __shared__ _Float16 Vl[3][64 * 64];

  const int tid = threadIdx.x;
  const int w = tid >> 6;
  const int l = tid & 63;
  const int q32 = l & 31;        // lane's q-row (and V d-row) index
  const int hi = l >> 5;

  // XCD-chunked bijective swizzle: 1024 blocks = 8 XCDs x 128.
  // wg bits: [bh:5][qt:4][half:1] -> consecutive wgs share (b,h) K/V panel.
  const int bid = blockIdx.x;
  const int wg = (bid & 7) * 128 + (bid >> 3);
  const int half = wg & 1;
  const int qt = (wg >> 1) & 15; // q-tile of 128 rows
  const int bh = wg >> 5;        // 0..31
  const int b = bh >> 4;
  const int h = bh & 15;

  const int qb = qt * 128 + w * 32;      // wave's first q row (32 rows/wave)
  const int hoff = h * DEPTH;
  const size_t kvoff = (size_t)bh * SEQ * DEPTH;

  // ---- Q B-fragments (n = q = q32, k-step c: dims c*16 + 8*hi + j), *log2e
  f16x8 qf[4];
  {
    const float* gq = q + (size_t)(b * SEQ + qb + q32) * DIMS + hoff + 8 * hi;
    #pragma unroll
    for (int c = 0; c < 4; ++c) {
      float4 a0 = *(const float4*)(gq + 16 * c);
      float4 a1 = *(const float4*)(gq + 16 * c + 4);
      float f[8] = {a0.x, a0.y, a0.z, a0.w, a1.x, a1.y, a1.z, a1.w};
      f16x8 t;
      #pragma unroll
      for (int j = 0; j < 8; ++j) t[j] = (_Float16)(f[j] * LOG2E);
      qf[c] = t;
    }
  }

  // ---- staging sources (per-lane pre-swizzle, octave-aware mask) ----
  const int j8 = l >> 3;
  const int sch0 = (l & 7) ^ j8 ^ ((2 * w) & 3);
  const int sch1 = sch0 ^ 1;
  const _Float16* gkA =
      kh + kvoff + (size_t)half * 1024 * DEPTH +
      (size_t)(16 * w + j8) * DEPTH + sch0 * 8;
  const _Float16* gkB =
      kh + kvoff + (size_t)half * 1024 * DEPTH +
      (size_t)(16 * w + 8 + j8) * DEPTH + sch1 * 8;
  const _Float16* gvA =
      vt + kvoff + (size_t)(16 * w + j8) * SEQ + half * 1024 + sch0 * 8;
  const _Float16* gvB =
      vt + kvoff + (size_t)(16 * w + 8 + j8) * SEQ + half * 1024 + sch1 * 8;

  // fragment-read offsets: chunk (2c+hi) of rows q32 / 32+q32 (same mask)
  const int mask0 = (q32 & 7) ^ ((q32 >> 3) & 3);
  int off[4];
  #pragma unroll
  for (int c = 0; c < 4; ++c) off[c] = ((2 * c + hi) ^ mask0) * 8;

  f32x16 acc0 = {}, acc1 = {};   // O: col d = q32 (+32), row q = crow(r,hi)
  f32x16 dacc = {};              // denominator, same C rows (cols replicated)
  float mrow = -3e38f;           // running max (log2 domain) for q-row q32

  const f16x8 onesf = {1, 1, 1, 1, 1, 1, 1, 1};

  auto stage = [&](int kb, int vb, int t) {
    const _Float16* gk1 = gkA + (size_t)t * 64 * DEPTH;
    const _Float16* gk2 = gkB + (size_t)t * 64 * DEPTH;
    const _Float16* gv1 = gvA + t * 64;
    const _Float16* gv2 = gvB + t * 64;
    GLOAD_LDS(gk1, &Kl[kb][(16 * w) * 64]);
    GLOAD_LDS(gk2, &Kl[kb][(16 * w + 8) * 64]);
    GLOAD_LDS(gv1, &Vl[vb][(16 * w) * 64]);
    GLOAD_LDS(gv2, &Vl[vb][(16 * w + 8) * 64]);
  };

  // QK^T swapped: st = mfma(K, Q): C[key][q], q = q32 lane-local
  auto qkt = [&](int kb, f32x16& s0, f32x16& s1) {
    f32x16 z = {};
    s0 = z; s1 = z;
    __builtin_amdgcn_s_setprio(1);
    #pragma unroll
    for (int c = 0; c < 4; ++c) {
      f16x8 kf0 = *(const f16x8*)&Kl[kb][q32 * 64 + off[c]];
      f16x8 kf1 = *(const f16x8*)&Kl[kb][(32 + q32) * 64 + off[c]];
      s0 = mfma32(kf0, qf[c], s0);
      s1 = mfma32(kf1, qf[c], s1);
    }
    __builtin_amdgcn_s_setprio(0);
  };

  auto smax_pv = [&](f32x16& st0, f32x16& st1, int vb) {
    // ---- online softmax: all 32 scores of q-row q32 are in-lane ----
    float mx = fmaxf(st0[0], st1[0]);
    #pragma unroll
    for (int r = 1; r < 16; ++r) mx = fmaxf(mx, fmaxf(st0[r], st1[r]));
    if (!__all(mx - mrow <= 8.0f)) {       // defer-max THR=8
      mx = fmaxf(mx, __shfl_xor(mx, 32));
      float mnew = fmaxf(mrow, mx);
      float sc = EXP2(mrow - mnew);
      mrow = mnew;
      #pragma unroll
      for (int r = 0; r < 16; ++r) {
        const int crow = (r & 3) + 8 * (r >> 2) + 4 * hi;
        float scb = __shfl(sc, crow);
        acc0[r] *= scb;
        acc1[r] *= scb;
        dacc[r] *= scb;
      }
    }
    float p0[16], p1[16];
    #pragma unroll
    for (int r = 0; r < 16; ++r) {
      p0[r] = EXP2(st0[r] - mrow);
      p1[r] = EXP2(st1[r] - mrow);
    }

    // ---- P -> PV A-fragments in-register (cvt_pk + permlane32_swap) ----
    f16x8 pa[4];
    auto mkpa = [&](const float* pp, f16x8* dst) {
      #pragma unroll
      for (int sl = 0; sl < 2; ++sl) {
        unsigned x0 = pkbits(pp[8 * sl + 0], pp[8 * sl + 1]);
        unsigned x1 = pkbits(pp[8 * sl + 2], pp[8 * sl + 3]);
        unsigned y0 = pkbits(pp[8 * sl + 4], pp[8 * sl + 5]);
        unsigned y1 = pkbits(pp[8 * sl + 6], pp[8 * sl + 7]);
        asm("v_permlane32_swap_b32 %0, %1" : "+v"(x0), "+v"(y0));
        asm("v_permlane32_swap_b32 %0, %1" : "+v"(x1), "+v"(y1));
        union { unsigned u[4]; f16x8 v; } pu;
        pu.u[0] = x0; pu.u[1] = x1; pu.u[2] = y0; pu.u[3] = y1;
        dst[sl] = pu.v;
      }
    };
    mkpa(p0, &pa[0]);
    mkpa(p1, &pa[2]);

    // ---- PV + den: acc += pa[s] x V^T rows; dacc += pa[s] x 1 ----
    __builtin_amdgcn_s_setprio(1);
    #pragma unroll
    for (int s = 0; s < 4; ++s) {
      f16x8 vf0 = *(const f16x8*)&Vl[vb][q32 * 64 + off[s]];
      f16x8 vf1 = *(const f16x8*)&Vl[vb][(32 + q32) * 64 + off[s]];
      acc0 = mfma32(pa[s], vf0, acc0);
      acc1 = mfma32(pa[s], vf1, acc1);
      dacc = mfma32(pa[s], onesf, dacc);
    }
    __builtin_amdgcn_s_setprio(0);
  };

  // ---- pipeline: QK^T one tile ahead of softmax/PV; 1 barrier per tile ----
  f32x16 stA0, stA1, stB0, stB1;
  stage(0, 0, 0);
  __syncthreads();               // tile 0 visible
  stage(1, 1, 1);
  qkt(0, stA0, stA1);            // scores(0)
  __syncthreads();               // tile 1 visible
  int va = 0;
  #pragma unroll 1
  for (int t = 0; t < HTILES; t += 2) {
    const int v1 = va == 2 ? 0 : va + 1;
    const int v2 = v1 == 2 ? 0 : v1 + 1;
    if (t + 2 < HTILES) stage(0, v2, t + 2);
    qkt(1, stB0, stB1);          // scores(t+1) — overlaps softmax(t) VALU
    smax_pv(stA0, stA1, va);
    __syncthreads();
    if (t + 3 < HTILES) stage(1, va, t + 3);
    if (t + 2 < HTILES) qkt(0, stA0, stA1);  // scores(t+2)
    smax_pv(stB0, stB1, v1);
    __syncthreads();
    va = v2;
  }

  // ---- epilogue: normalized fp16 partial O + (m, den) stats ----
  const size_t rbase = (size_t)half * NROWS + (size_t)bh * SEQ + qb;
  _Float16* po = opart + rbase * 64;
  #pragma unroll
  for (int r = 0; r < 16; ++r) {
    const int crow = (r & 3) + 8 * (r >> 2) + 4 * hi;
    float rden = 1.0f / dacc[r];
    _Float16* pr = po + (size_t)crow * 64;
    pr[q32] = (_Float16)(acc0[r] * rden);
    pr[32 + q32] = (_Float16)(acc1[r] * rden);
    if (q32 == crow)             // exactly one lane per output row
      stats[rbase + crow] = make_float2(mrow, dacc[r]);
  }
}

// ---------- combine: merge the two split-K halves ----------
__global__ __launch_bounds__(256) void combine(
    const _Float16* __restrict__ opart, const float2* __restrict__ stats,
    float* __restrict__ out) {
  int t = blockIdx.x * 256 + threadIdx.x;   // 524288 threads
  int rowg = t >> 3;
  int dc = (t & 7) * 8;
  float2 s0 = stats[rowg];
  float2 s1 = stats[NROWS + rowg];
  float M = fmaxf(s0.x, s1.x);
  float w0 = s0.y * EXP2(s0.x - M);
  float w1 = s1.y * EXP2(s1.x - M);
  float inv = 1.0f / (w0 + w1);
  w0 *= inv;
  w1 *= inv;
  f16x8 a = *(const f16x8*)(opart + (size_t)rowg * 64 + dc);
  f16x8 c = *(const f16x8*)(opart + (size_t)NROWS * 64 + (size_t)rowg * 64 + dc);
  int bh = rowg >> 11;           // rowg = bh*2048 + s
  int s = rowg & 2047;
  int b = bh >> 4, h = bh & 15;
  float* o = out + ((size_t)(b * SEQ + s)) * DIMS + h * DEPTH + dc;
  float res[8];
  #pragma unroll
  for (int j = 0; j < 8; ++j) res[j] = w0 * (float)a[j] + w1 * (float)c[j];
  *(float4*)o = *(float4*)&res[0];
  *(float4*)(o + 4) = *(float4*)&res[4];
}

extern "C" void kernel_launch(void* const* d_in, const int* in_sizes, int n_in,
                              void* d_out, int out_size, void* d_ws, size_t ws_size,
                              hipStream_t stream) {
  const float* q = (const float*)d_in[0];
  const float* k = (const float*)d_in[1];
  const float* v = (const float*)d_in[2];
  float* out = (float*)d_out;

  // workspace: Khf (8MB) | Vt (8MB) | opart (16MB) | stats (1MB)
  const size_t tsz = (size_t)2 * HEADS * SEQ * DEPTH;  // 4M elements
  _Float16* khf = (_Float16*)d_ws;
  _Float16* vtp = khf + tsz;
  _Float16* opart = vtp + tsz;
  float2* stats = (float2*)(opart + (size_t)2 * NROWS * 64);

  prep_kv<<<4096, 256, 0, stream>>>(k, v, khf, vtp);
  attn_fwd<<<1024, 256, 0, stream>>>(q, khf, vtp, opart, stats);
  combine<<<2048, 256, 0, stream>>>(opart, stats, out);
}

// Round 13
// 80.362 us; speedup vs baseline: 3.7927x; 3.7927x over previous
//
#include <hip/hip_runtime.h>

#define SEQ 2048
#define HEADS 16
#define DEPTH 64
#define DIMS 1024
#define LOG2E 1.44269504088896340736f
#define NROWS 65536            // total q rows = 2*16*2048
#define HTILES 16              // 1024 keys per half / 64

typedef _Float16 f16x8 __attribute__((ext_vector_type(8)));
typedef __fp16 fp16v2 __attribute__((ext_vector_type(2)));
typedef float f32x16 __attribute__((ext_vector_type(16)));

__device__ __forceinline__ f32x16 mfma32(f16x8 a, f16x8 b, f32x16 c) {
  return __builtin_amdgcn_mfma_f32_32x32x16_f16(a, b, c, 0, 0, 0);
}

#if __has_builtin(__builtin_amdgcn_exp2f)
#define EXP2(x) __builtin_amdgcn_exp2f(x)
#else
#define EXP2(x) exp2f(x)
#endif

__device__ __forceinline__ unsigned pkbits(float a, float b) {
  union { fp16v2 h; unsigned u; } cv;
  cv.h = __builtin_amdgcn_cvt_pkrtz(a, b);
  return cv.u;
}

// direct global->LDS DMA, 16B/lane; LDS dest = wave-uniform base + lane*16
#define GLOAD_LDS(g, l)                                                        \
  __builtin_amdgcn_global_load_lds(                                            \
      (const __attribute__((address_space(1))) unsigned int*)(g),              \
      (__attribute__((address_space(3))) unsigned int*)(l), 16, 0, 0)

// ---------- fused prepass: K -> fp16 [bh][S][D];  V -> fp16 [bh][D][S] ------
__global__ __launch_bounds__(256) void prep_kv(const float* __restrict__ k,
                                               const float* __restrict__ v,
                                               _Float16* __restrict__ khf,
                                               _Float16* __restrict__ vtp) {
  const int bid = blockIdx.x;
  if (bid < 2048) {              // ---- K half: one thread per 8 elems ----
    int t = bid * 256 + threadIdx.x;
    size_t flat = (size_t)t * 8;
    int b = (int)(flat >> 21);                    // S*DIMS = 2^21
    int rem = (int)(flat & ((1u << 21) - 1));
    int s = rem >> 10;
    int c = rem & 1023;
    int h = c >> 6;
    int d = c & 63;
    float4 a0 = *(const float4*)(k + flat);
    float4 a1 = *(const float4*)(k + flat + 4);
    float f[8] = {a0.x, a0.y, a0.z, a0.w, a1.x, a1.y, a1.z, a1.w};
    f16x8 th;
    #pragma unroll
    for (int j = 0; j < 8; ++j) th[j] = (_Float16)f[j];
    size_t o = ((size_t)(b * HEADS + h) * SEQ + s) * DEPTH + d;
    *(f16x8*)(khf + o) = th;
  } else {                       // ---- V half: transpose to [bh][D][S] ----
    int t = (bid - 2048) * 256 + threadIdx.x;
    int d = t & 63;
    int sg = (t >> 6) & 255;
    int bh = t >> 14;
    int b = bh >> 4, h = bh & 15;
    int s0 = sg * 8;
    const float* src = v + ((size_t)(b * SEQ + s0)) * DIMS + h * DEPTH + d;
    _Float16* dst = vtp + ((size_t)bh * DEPTH + d) * SEQ + s0;
    f16x8 tv;
    #pragma unroll
    for (int i = 0; i < 8; ++i) tv[i] = (_Float16)src[(size_t)i * DIMS];
    *(f16x8*)dst = tv;
  }
}

// ---------- main: flash attention, split-K x2, 32x32x16 MFMA ----------
// Each block handles 1024 keys (half the sequence) for 128 q-rows, writing
// normalized fp16 partial O + per-row (m, den) stats. LDS swizzle: 16B chunk
// c of row r at chunk c ^ ((r&7)^((r>>3)&3)) -> conflict-free b128 reads.
// P stays in registers (cvt_pk + v_permlane32_swap). Lean register set:
// no score-ahead, scalar den, exp-in-place -> fits without spilling.
__global__ __launch_bounds__(256, 3) void attn_fwd(
    const float* __restrict__ q, const _Float16* __restrict__ kh,
    const _Float16* __restrict__ vt, _Float16* __restrict__ opart,
    float2* __restrict__ stats) {
  __shared__ _Float16 Kl[2][64 * 64];
  __shared__ _Float16 Vl[2][64 * 64];

  const int tid = threadIdx.x;
  const int w = tid >> 6;
  const int l = tid & 63;
  const int q32 = l & 31;        // lane's q-row (and V d-row) index
  const int hi = l >> 5;

  // XCD-chunked bijective swizzle: 1024 blocks = 8 XCDs x 128.
  // wg bits: [bh:5][qt:4][half:1] -> consecutive wgs share (b,h) K/V panel.
  const int bid = blockIdx.x;
  const int wg = (bid & 7) * 128 + (bid >> 3);
  const int half = wg & 1;
  const int qt = (wg >> 1) & 15; // q-tile of 128 rows
  const int bh = wg >> 5;        // 0..31
  const int b = bh >> 4;
  const int h = bh & 15;

  const int qb = qt * 128 + w * 32;      // wave's first q row (32 rows/wave)
  const int hoff = h * DEPTH;
  const size_t kvoff = (size_t)bh * SEQ * DEPTH;

  // ---- Q B-fragments (n = q = q32, k-step c: dims c*16 + 8*hi + j), *log2e
  f16x8 qf[4];
  {
    const float* gq = q + (size_t)(b * SEQ + qb + q32) * DIMS + hoff + 8 * hi;
    #pragma unroll
    for (int c = 0; c < 4; ++c) {
      float4 a0 = *(const float4*)(gq + 16 * c);
      float4 a1 = *(const float4*)(gq + 16 * c + 4);
      float f[8] = {a0.x, a0.y, a0.z, a0.w, a1.x, a1.y, a1.z, a1.w};
      f16x8 t;
      #pragma unroll
      for (int j = 0; j < 8; ++j) t[j] = (_Float16)(f[j] * LOG2E);
      qf[c] = t;
    }
  }

  // ---- staging sources (per-lane pre-swizzle, octave-aware mask) ----
  const int j8 = l >> 3;
  const int sch0 = (l & 7) ^ j8 ^ ((2 * w) & 3);
  const int sch1 = sch0 ^ 1;
  const _Float16* gkA =
      kh + kvoff + (size_t)half * 1024 * DEPTH +
      (size_t)(16 * w + j8) * DEPTH + sch0 * 8;
  const _Float16* gkB =
      kh + kvoff + (size_t)half * 1024 * DEPTH +
      (size_t)(16 * w + 8 + j8) * DEPTH + sch1 * 8;
  const _Float16* gvA =
      vt + kvoff + (size_t)(16 * w + j8) * SEQ + half * 1024 + sch0 * 8;
  const _Float16* gvB =
      vt + kvoff + (size_t)(16 * w + 8 + j8) * SEQ + half * 1024 + sch1 * 8;

  // fragment-read offsets: chunk (2c+hi) of rows q32 / 32+q32 (same mask)
  const int mask0 = (q32 & 7) ^ ((q32 >> 3) & 3);
  int off[4];
  #pragma unroll
  for (int c = 0; c < 4; ++c) off[c] = ((2 * c + hi) ^ mask0) * 8;

  f32x16 acc0 = {}, acc1 = {};   // O: col d = q32 (+32), row q = crow(r,hi)
  float den = 0.f;               // lane-local denominator for q-row q32
  float mrow = -3e38f;           // running max (log2 domain) for q-row q32

  auto stage = [&](int buf, int t) {
    const _Float16* gk1 = gkA + (size_t)t * 64 * DEPTH;
    const _Float16* gk2 = gkB + (size_t)t * 64 * DEPTH;
    const _Float16* gv1 = gvA + t * 64;
    const _Float16* gv2 = gvB + t * 64;
    GLOAD_LDS(gk1, &Kl[buf][(16 * w) * 64]);
    GLOAD_LDS(gk2, &Kl[buf][(16 * w + 8) * 64]);
    GLOAD_LDS(gv1, &Vl[buf][(16 * w) * 64]);
    GLOAD_LDS(gv2, &Vl[buf][(16 * w + 8) * 64]);
  };

  auto compute = [&](int buf) {
    // ---- QK^T swapped: st = mfma(K, Q): C[key][q], q = q32 lane-local ----
    f32x16 st0 = {}, st1 = {};
    __builtin_amdgcn_s_setprio(1);
    #pragma unroll
    for (int c = 0; c < 4; ++c) {
      f16x8 kf0 = *(const f16x8*)&Kl[buf][q32 * 64 + off[c]];
      f16x8 kf1 = *(const f16x8*)&Kl[buf][(32 + q32) * 64 + off[c]];
      st0 = mfma32(kf0, qf[c], st0);
      st1 = mfma32(kf1, qf[c], st1);
    }
    __builtin_amdgcn_s_setprio(0);

    // ---- online softmax: all 32 scores of q-row q32 are in-lane ----
    float mx = fmaxf(st0[0], st1[0]);
    #pragma unroll
    for (int r = 1; r < 16; ++r) mx = fmaxf(mx, fmaxf(st0[r], st1[r]));
    if (!__all(mx - mrow <= 8.0f)) {       // defer-max THR=8
      mx = fmaxf(mx, __shfl_xor(mx, 32));
      float mnew = fmaxf(mrow, mx);
      float sc = EXP2(mrow - mnew);
      mrow = mnew;
      den *= sc;                           // den is lane-local -> no shfl
      #pragma unroll
      for (int r = 0; r < 16; ++r) {
        const int crow = (r & 3) + 8 * (r >> 2) + 4 * hi;
        float scb = __shfl(sc, crow);
        acc0[r] *= scb;
        acc1[r] *= scb;
      }
    }
    // exp in place (st becomes P), accumulate row-sum
    float rs = 0.f;
    #pragma unroll
    for (int r = 0; r < 16; ++r) {
      st0[r] = EXP2(st0[r] - mrow);
      st1[r] = EXP2(st1[r] - mrow);
      rs += st0[r] + st1[r];
    }
    rs += __shfl_xor(rs, 32);
    den += rs;

    // ---- P -> PV A-fragments in-register (cvt_pk + permlane32_swap) ----
    f16x8 pa[4];
    auto mkpa = [&](const f32x16& pp, f16x8* dst) {
      #pragma unroll
      for (int sl = 0; sl < 2; ++sl) {
        unsigned x0 = pkbits(pp[8 * sl + 0], pp[8 * sl + 1]);
        unsigned x1 = pkbits(pp[8 * sl + 2], pp[8 * sl + 3]);
        unsigned y0 = pkbits(pp[8 * sl + 4], pp[8 * sl + 5]);
        unsigned y1 = pkbits(pp[8 * sl + 6], pp[8 * sl + 7]);
        asm("v_permlane32_swap_b32 %0, %1" : "+v"(x0), "+v"(y0));
        asm("v_permlane32_swap_b32 %0, %1" : "+v"(x1), "+v"(y1));
        union { unsigned u[4]; f16x8 v; } pu;
        pu.u[0] = x0; pu.u[1] = x1; pu.u[2] = y0; pu.u[3] = y1;
        dst[sl] = pu.v;
      }
    };
    mkpa(st0, &pa[0]);
    mkpa(st1, &pa[2]);

    // ---- PV: acc += pa[s] x V^T rows ----
    __builtin_amdgcn_s_setprio(1);
    #pragma unroll
    for (int s = 0; s < 4; ++s) {
      f16x8 vf0 = *(const f16x8*)&Vl[buf][q32 * 64 + off[s]];
      f16x8 vf1 = *(const f16x8*)&Vl[buf][(32 + q32) * 64 + off[s]];
      acc0 = mfma32(pa[s], vf0, acc0);
      acc1 = mfma32(pa[s], vf1, acc1);
    }
    __builtin_amdgcn_s_setprio(0);
  };

  // ---- 2-phase pipeline: stage t+1 early, ONE barrier per tile ----
  stage(0, 0);
  __syncthreads();                      // drains vmcnt -> tile 0 visible
  #pragma unroll 1
  for (int kt = 0; kt < HTILES; kt += 2) {
    stage(1, kt + 1);                   // in flight during compute
    compute(0);
    __syncthreads();                    // drain + WAR fence
    if (kt + 2 < HTILES) stage(0, kt + 2);
    compute(1);
    __syncthreads();
  }

  // ---- epilogue: normalized fp16 partial O + (m, den) stats ----
  const size_t rbase = (size_t)half * NROWS + (size_t)bh * SEQ + qb;
  _Float16* po = opart + rbase * 64;
  #pragma unroll
  for (int r = 0; r < 16; ++r) {
    const int crow = (r & 3) + 8 * (r >> 2) + 4 * hi;
    float rden = 1.0f / __shfl(den, crow);   // den equal across hi halves
    _Float16* pr = po + (size_t)crow * 64;
    pr[q32] = (_Float16)(acc0[r] * rden);
    pr[32 + q32] = (_Float16)(acc1[r] * rden);
    if (q32 == crow)             // this lane's own row -> lane-local stats
      stats[rbase + crow] = make_float2(mrow, den);
  }
}

// ---------- combine: merge the two split-K halves ----------
__global__ __launch_bounds__(256) void combine(
    const _Float16* __restrict__ opart, const float2* __restrict__ stats,
    float* __restrict__ out) {
  int t = blockIdx.x * 256 + threadIdx.x;   // 524288 threads
  int rowg = t >> 3;
  int dc = (t & 7) * 8;
  float2 s0 = stats[rowg];
  float2 s1 = stats[NROWS + rowg];
  float M = fmaxf(s0.x, s1.x);
  float w0 = s0.y * EXP2(s0.x - M);
  float w1 = s1.y * EXP2(s1.x - M);
  float inv = 1.0f / (w0 + w1);
  w0 *= inv;
  w1 *= inv;
  f16x8 a = *(const f16x8*)(opart + (size_t)rowg * 64 + dc);
  f16x8 c = *(const f16x8*)(opart + (size_t)NROWS * 64 + (size_t)rowg * 64 + dc);
  int bh = rowg >> 11;           // rowg = bh*2048 + s
  int s = rowg & 2047;
  int b = bh >> 4, h = bh & 15;
  float* o = out + ((size_t)(b * SEQ + s)) * DIMS + h * DEPTH + dc;
  float res[8];
  #pragma unroll
  for (int j = 0; j < 8; ++j) res[j] = w0 * (float)a[j] + w1 * (float)c[j];
  *(float4*)o = *(float4*)&res[0];
  *(float4*)(o + 4) = *(float4*)&res[4];
}

extern "C" void kernel_launch(void* const* d_in, const int* in_sizes, int n_in,
                              void* d_out, int out_size, void* d_ws, size_t ws_size,
                              hipStream_t stream) {
  const float* q = (const float*)d_in[0];
  const float* k = (const float*)d_in[1];
  const float* v = (const float*)d_in[2];
  float* out = (float*)d_out;

  // workspace: Khf (8MB) | Vt (8MB) | opart (16MB) | stats (1MB)
  const size_t tsz = (size_t)2 * HEADS * SEQ * DEPTH;  // 4M elements
  _Float16* khf = (_Float16*)d_ws;
  _Float16* vtp = khf + tsz;
  _Float16* opart = vtp + tsz;
  float2* stats = (float2*)(opart + (size_t)2 * NROWS * 64);

  prep_kv<<<4096, 256, 0, stream>>>(k, v, khf, vtp);
  attn_fwd<<<1024, 256, 0, stream>>>(q, khf, vtp, opart, stats);
  combine<<<2048, 256, 0, stream>>>(opart, stats, out);
}